// Round 4
// baseline (342.812 us; speedup 1.0000x reference)
//
#include <hip/hip_runtime.h>
#include <hip/hip_bf16.h>

// DotProductAttention B=2,H=16,S=2048,D=64 fp32 in/out, int32 mask (B,1,S,S).
// R3: R2 structure + (1) register-prefetch pipeline: chunk t+1's K/V/mask
//     global loads issue BEFORE chunk t's compute, so their ~600cyc latency
//     overlaps compute instead of sitting inside the barrier-to-barrier
//     staging section. (2) duplicate-source __shfl (4 readers/source ->
//     crossbar serialization, suspected SQ_LDS_BANK_CONFLICT source)
//     replaced with same-address LDS broadcast reads (conflict-free).
//  - S^T = K*Q^T so softmax stats live one-query-per-lane-column.
//  - base-2 softmax (0.125*log2e folded into Q, mask -> -1e9*log2e).
//  - P: C-layout -> A-layout via per-wave LDS round trip.
//  - V transposed in LDS [d][key]; rows 144 B for aligned b128.

#define B_ 2
#define H_ 16
#define S_ 2048
#define D_ 64
#define BQ 64
#define BK 64
#define PADW 72   // LDS row stride in bf16 elems (144 bytes)

typedef __attribute__((ext_vector_type(4))) float f32x4;
typedef __attribute__((ext_vector_type(8))) short bf16x8;
typedef __attribute__((ext_vector_type(4))) short bf16x4;

#define QSCALE 0.1803368801111137f       // 0.125 * log2(e)
#define MASKNEG (-1.4426950408889634e9f) // -1e9 * log2(e)

static __device__ __forceinline__ short f2bf(float f) {
  __hip_bfloat16 h = __float2bfloat16(f);
  short s; __builtin_memcpy(&s, &h, sizeof(s)); return s;
}
static __device__ __forceinline__ float fexp2(float x) {
  return __builtin_amdgcn_exp2f(x);
}

__global__ __launch_bounds__(256, 4)
void attn_mfma(const float* __restrict__ qg, const float* __restrict__ kg,
               const float* __restrict__ vg, const int* __restrict__ maskg,
               float* __restrict__ outg) {
  __shared__ short sK[BK][PADW];      // [key][d]   bf16
  __shared__ short sVT[D_][PADW];     // [d][key]   bf16 (transposed V)
  __shared__ short sP[4][16][PADW];   // per-wave P [q][key] bf16
  __shared__ float sA[4][16];         // per-wave stats broadcast buffer

  const int tid  = threadIdx.x;
  const int lane = tid & 63;
  const int wv   = tid >> 6;
  const int l15  = lane & 15;
  const int quad = lane >> 4;

  const int bh = blockIdx.y;          // 0..31
  const int b  = bh >> 4;
  const int q0 = blockIdx.x * BQ;
  const int qw = q0 + wv * 16 + l15;  // this lane's stats-query row

  // ---- Q fragments (B-operand: lane holds Q[q=l15][d=ks*32+quad*8+j]) ----
  bf16x8 qf[2];
  {
    const float* qrow = qg + ((size_t)bh * S_ + qw) * D_;
    #pragma unroll
    for (int ks = 0; ks < 2; ++ks) {
      const float4 u0 = *(const float4*)(qrow + ks*32 + quad*8);
      const float4 u1 = *(const float4*)(qrow + ks*32 + quad*8 + 4);
      bf16x8 f;
      f[0]=f2bf(u0.x*QSCALE); f[1]=f2bf(u0.y*QSCALE);
      f[2]=f2bf(u0.z*QSCALE); f[3]=f2bf(u0.w*QSCALE);
      f[4]=f2bf(u1.x*QSCALE); f[5]=f2bf(u1.y*QSCALE);
      f[6]=f2bf(u1.z*QSCALE); f[7]=f2bf(u1.w*QSCALE);
      qf[ks] = f;
    }
  }

  f32x4 O[4];
  #pragma unroll
  for (int dt = 0; dt < 4; ++dt) O[dt] = (f32x4){0.f, 0.f, 0.f, 0.f};
  float m = -3.0e38f, l = 0.f;

  const float* kbase = kg + (size_t)bh * S_ * D_;
  const float* vbase = vg + (size_t)bh * S_ * D_;
  const int*   mrow  = maskg + ((size_t)b * S_ + qw) * S_;

  // ---- prefetch pipeline registers: chunk t+1's K/V/mask ----
  float4 kpre[4];     // K: thread loads rows id>>4, cols (id&15)*4
  float4 vpre[4];     // V: pairs for the transpose-pack
  int4   mpre[4];     // this lane's mask, 16 keys

  // prologue: load chunk 0
  #pragma unroll
  for (int i = 0; i < 4; ++i) {
    const int id = tid + 256*i;
    kpre[i] = *(const float4*)(kbase + (size_t)(id >> 4)*D_ + (id & 15)*4);
  }
  #pragma unroll
  for (int i = 0; i < 2; ++i) {
    const int id = tid + 256*i;
    const int kp = id & 31, d4 = (id >> 5) * 4;
    vpre[2*i]   = *(const float4*)(vbase + (size_t)(2*kp    )*D_ + d4);
    vpre[2*i+1] = *(const float4*)(vbase + (size_t)(2*kp + 1)*D_ + d4);
  }
  #pragma unroll
  for (int mt = 0; mt < 4; ++mt)
    mpre[mt] = *(const int4*)(mrow + mt*16 + quad*4);

  for (int t0 = 0; t0 < S_; t0 += BK) {
    __syncthreads();
    // ---- stage prefetched K tile [key][d], fp32->bf16 ----
    #pragma unroll
    for (int i = 0; i < 4; ++i) {
      const int id = tid + 256*i;
      const int key = id >> 4, d4 = (id & 15) * 4;
      const float4 u = kpre[i];
      bf16x4 w; w[0]=f2bf(u.x); w[1]=f2bf(u.y); w[2]=f2bf(u.z); w[3]=f2bf(u.w);
      *(bf16x4*)&sK[key][d4] = w;
    }
    // ---- stage prefetched V^T tile [d][key] ----
    #pragma unroll
    for (int i = 0; i < 2; ++i) {
      const int id = tid + 256*i;
      const int kp = id & 31, d4 = (id >> 5) * 4;
      const float4 a = vpre[2*i];
      const float4 c = vpre[2*i+1];
      const float av[4] = {a.x, a.y, a.z, a.w};
      const float cv[4] = {c.x, c.y, c.z, c.w};
      #pragma unroll
      for (int j = 0; j < 4; ++j) {
        const unsigned pk = (unsigned)(unsigned short)f2bf(av[j])
                          | ((unsigned)(unsigned short)f2bf(cv[j]) << 16);
        *(unsigned*)&sVT[d4 + j][2*kp] = pk;
      }
    }
    // current chunk's mask out of the pipeline regs
    int4 mk[4];
    #pragma unroll
    for (int mt = 0; mt < 4; ++mt) mk[mt] = mpre[mt];
    __syncthreads();

    // ---- issue next chunk's global loads NOW; latency hides under compute
    const int tn = t0 + BK;
    if (tn < S_) {
      const float* kb = kbase + (size_t)tn * D_;
      const float* vb = vbase + (size_t)tn * D_;
      #pragma unroll
      for (int i = 0; i < 4; ++i) {
        const int id = tid + 256*i;
        kpre[i] = *(const float4*)(kb + (size_t)(id >> 4)*D_ + (id & 15)*4);
      }
      #pragma unroll
      for (int i = 0; i < 2; ++i) {
        const int id = tid + 256*i;
        const int kp = id & 31, d4 = (id >> 5) * 4;
        vpre[2*i]   = *(const float4*)(vb + (size_t)(2*kp    )*D_ + d4);
        vpre[2*i+1] = *(const float4*)(vb + (size_t)(2*kp + 1)*D_ + d4);
      }
      #pragma unroll
      for (int mt = 0; mt < 4; ++mt)
        mpre[mt] = *(const int4*)(mrow + tn + mt*16 + quad*4);
    }

    // ---- S^T = K * Q^T : C[row=key=quad*4+r (tile mt)][col=q=l15] ----
    f32x4 st[4];
    #pragma unroll
    for (int mt = 0; mt < 4; ++mt) {
      f32x4 acc = (f32x4){0.f, 0.f, 0.f, 0.f};
      #pragma unroll
      for (int ks = 0; ks < 2; ++ks) {
        const bf16x8 kf = *(const bf16x8*)&sK[mt*16 + l15][ks*32 + quad*8];
        acc = __builtin_amdgcn_mfma_f32_16x16x32_bf16(kf, qf[ks], acc, 0, 0, 0);
      }
      st[mt] = acc;
    }

    // ---- mask + chunk max ----
    float cmax = -3.0e38f;
    #pragma unroll
    for (int mt = 0; mt < 4; ++mt) {
      f32x4 s = st[mt];
      s.x = mk[mt].x ? s.x : MASKNEG;
      s.y = mk[mt].y ? s.y : MASKNEG;
      s.z = mk[mt].z ? s.z : MASKNEG;
      s.w = mk[mt].w ? s.w : MASKNEG;
      st[mt] = s;
      cmax = fmaxf(cmax, fmaxf(fmaxf(s.x, s.y), fmaxf(s.z, s.w)));
    }
    cmax = fmaxf(cmax, __shfl_xor(cmax, 16));   // bijective shuffles: free
    cmax = fmaxf(cmax, __shfl_xor(cmax, 32));
    const float mnew  = fmaxf(m, cmax);
    const float alpha = fexp2(m - mnew);   // ==0 on first chunk (m=-3e38)
    m = mnew;

    // broadcast alpha via LDS (replaces 4 duplicate-source shuffles);
    // alpha is quad-uniform per l15, so one quad writes
    if (quad == 0) sA[wv][l15] = alpha;

    // ---- P = exp2(S - m), accumulate l, write P to per-wave LDS ----
    float lsum = 0.f;
    #pragma unroll
    for (int mt = 0; mt < 4; ++mt) {
      const float p0 = fexp2(st[mt].x - mnew);
      const float p1 = fexp2(st[mt].y - mnew);
      const float p2 = fexp2(st[mt].z - mnew);
      const float p3 = fexp2(st[mt].w - mnew);
      lsum += (p0 + p1) + (p2 + p3);
      bf16x4 pw; pw[0]=f2bf(p0); pw[1]=f2bf(p1); pw[2]=f2bf(p2); pw[3]=f2bf(p3);
      *(bf16x4*)&sP[wv][l15][mt*16 + quad*4] = pw;
    }
    // each quad-replica holds only 16/64 chunk keys: reduce across quads
    lsum += __shfl_xor(lsum, 16);
    lsum += __shfl_xor(lsum, 32);
    l = l * alpha + lsum;

    // wave-internal: drain ds ops (sP + sA visible across lanes of this wave)
    asm volatile("s_waitcnt lgkmcnt(0)" ::: "memory");

    // ---- rescale O (O-rows are q=quad*4+r); same-address b128 broadcast ----
    const float4 ar = *(const float4*)&sA[wv][quad*4];
    #pragma unroll
    for (int dt = 0; dt < 4; ++dt) {
      O[dt].x *= ar.x; O[dt].y *= ar.y; O[dt].z *= ar.z; O[dt].w *= ar.w;
    }

    // ---- O += P * V ----
    const bf16x8 pf0 = *(const bf16x8*)&sP[wv][l15][quad*8];
    const bf16x8 pf1 = *(const bf16x8*)&sP[wv][l15][32 + quad*8];
    #pragma unroll
    for (int dt = 0; dt < 4; ++dt) {
      const bf16x8 vf0 = *(const bf16x8*)&sVT[dt*16 + l15][quad*8];
      const bf16x8 vf1 = *(const bf16x8*)&sVT[dt*16 + l15][32 + quad*8];
      O[dt] = __builtin_amdgcn_mfma_f32_16x16x32_bf16(pf0, vf0, O[dt], 0, 0, 0);
      O[dt] = __builtin_amdgcn_mfma_f32_16x16x32_bf16(pf1, vf1, O[dt], 0, 0, 0);
    }
  }

  // ---- epilogue: normalize by l (per O-row), store ----
  if (quad == 0) sA[wv][l15] = l;
  asm volatile("s_waitcnt lgkmcnt(0)" ::: "memory");
  const float4 lv = *(const float4*)&sA[wv][quad*4];
  const float ir0 = 1.0f / lv.x, ir1 = 1.0f / lv.y;
  const float ir2 = 1.0f / lv.z, ir3 = 1.0f / lv.w;

  float* ob = outg + ((size_t)bh * S_ + q0 + wv*16) * D_;
  #pragma unroll
  for (int dt = 0; dt < 4; ++dt) {
    ob[(quad*4 + 0)*D_ + dt*16 + l15] = O[dt].x * ir0;
    ob[(quad*4 + 1)*D_ + dt*16 + l15] = O[dt].y * ir1;
    ob[(quad*4 + 2)*D_ + dt*16 + l15] = O[dt].z * ir2;
    ob[(quad*4 + 3)*D_ + dt*16 + l15] = O[dt].w * ir3;
  }
}

extern "C" void kernel_launch(void* const* d_in, const int* in_sizes, int n_in,
                              void* d_out, int out_size, void* d_ws, size_t ws_size,
                              hipStream_t stream) {
  const float* q    = (const float*)d_in[0];
  const float* k    = (const float*)d_in[1];
  const float* v    = (const float*)d_in[2];
  const int*   mask = (const int*)d_in[3];
  float* out = (float*)d_out;

  dim3 grid(S_ / BQ, B_ * H_);   // (32, 32) = 1024 blocks, 4 waves each
  attn_mfma<<<grid, 256, 0, stream>>>(q, k, v, mask, out);
}

// Round 5
// 264.523 us; speedup vs baseline: 1.2960x; 1.2960x over previous
//
#include <hip/hip_runtime.h>
#include <hip/hip_bf16.h>

// DotProductAttention B=2,H=16,S=2048,D=64 fp32 in/out, int32 mask (B,1,S,S).
// R4: R3 register-prefetch pipeline, but fix the spill R3's counters exposed
//     (WRITE_SIZE 16->200MB = scratch):
//     (a) __launch_bounds__(256,2): VGPR cap 256 so the 32-reg K/V prefetch
//         fits; actual use ~110 still allows 4 waves/SIMD.
//     (b) drop mask prefetch (16 regs): mask is L2-resident (16 blocks/b
//         share it), load it at compute-phase start under the MFMA chain.
//  - S^T = K*Q^T so softmax stats live one-query-per-lane-column.
//  - base-2 softmax (0.125*log2e folded into Q, mask -> -1e9*log2e).
//  - P: C-layout -> A-layout via per-wave LDS round trip.
//  - V transposed in LDS [d][key]; rows 144 B for aligned b128.

#define B_ 2
#define H_ 16
#define S_ 2048
#define D_ 64
#define BQ 64
#define BK 64
#define PADW 72   // LDS row stride in bf16 elems (144 bytes)

typedef __attribute__((ext_vector_type(4))) float f32x4;
typedef __attribute__((ext_vector_type(8))) short bf16x8;
typedef __attribute__((ext_vector_type(4))) short bf16x4;

#define QSCALE 0.1803368801111137f       // 0.125 * log2(e)
#define MASKNEG (-1.4426950408889634e9f) // -1e9 * log2(e)

static __device__ __forceinline__ short f2bf(float f) {
  __hip_bfloat16 h = __float2bfloat16(f);
  short s; __builtin_memcpy(&s, &h, sizeof(s)); return s;
}
static __device__ __forceinline__ float fexp2(float x) {
  return __builtin_amdgcn_exp2f(x);
}

__global__ __launch_bounds__(256, 2)
void attn_mfma(const float* __restrict__ qg, const float* __restrict__ kg,
               const float* __restrict__ vg, const int* __restrict__ maskg,
               float* __restrict__ outg) {
  __shared__ short sK[BK][PADW];      // [key][d]   bf16
  __shared__ short sVT[D_][PADW];     // [d][key]   bf16 (transposed V)
  __shared__ short sP[4][16][PADW];   // per-wave P [q][key] bf16
  __shared__ float sA[4][16];         // per-wave stats broadcast buffer

  const int tid  = threadIdx.x;
  const int lane = tid & 63;
  const int wv   = tid >> 6;
  const int l15  = lane & 15;
  const int quad = lane >> 4;

  const int bh = blockIdx.y;          // 0..31
  const int b  = bh >> 4;
  const int q0 = blockIdx.x * BQ;
  const int qw = q0 + wv * 16 + l15;  // this lane's stats-query row

  // ---- Q fragments (B-operand: lane holds Q[q=l15][d=ks*32+quad*8+j]) ----
  bf16x8 qf[2];
  {
    const float* qrow = qg + ((size_t)bh * S_ + qw) * D_;
    #pragma unroll
    for (int ks = 0; ks < 2; ++ks) {
      const float4 u0 = *(const float4*)(qrow + ks*32 + quad*8);
      const float4 u1 = *(const float4*)(qrow + ks*32 + quad*8 + 4);
      bf16x8 f;
      f[0]=f2bf(u0.x*QSCALE); f[1]=f2bf(u0.y*QSCALE);
      f[2]=f2bf(u0.z*QSCALE); f[3]=f2bf(u0.w*QSCALE);
      f[4]=f2bf(u1.x*QSCALE); f[5]=f2bf(u1.y*QSCALE);
      f[6]=f2bf(u1.z*QSCALE); f[7]=f2bf(u1.w*QSCALE);
      qf[ks] = f;
    }
  }

  f32x4 O[4];
  #pragma unroll
  for (int dt = 0; dt < 4; ++dt) O[dt] = (f32x4){0.f, 0.f, 0.f, 0.f};
  float m = -3.0e38f, l = 0.f;

  const float* kbase = kg + (size_t)bh * S_ * D_;
  const float* vbase = vg + (size_t)bh * S_ * D_;
  const int*   mrow  = maskg + ((size_t)b * S_ + qw) * S_;

  // ---- prefetch pipeline registers: chunk t+1's K/V (32 VGPRs) ----
  float4 kpre[4];     // K: thread loads row id>>4, cols (id&15)*4
  float4 vpre[4];     // V: key-pairs for the transpose-pack

  // prologue: load chunk 0
  #pragma unroll
  for (int i = 0; i < 4; ++i) {
    const int id = tid + 256*i;
    kpre[i] = *(const float4*)(kbase + (size_t)(id >> 4)*D_ + (id & 15)*4);
  }
  #pragma unroll
  for (int i = 0; i < 2; ++i) {
    const int id = tid + 256*i;
    const int kp = id & 31, d4 = (id >> 5) * 4;
    vpre[2*i]   = *(const float4*)(vbase + (size_t)(2*kp    )*D_ + d4);
    vpre[2*i+1] = *(const float4*)(vbase + (size_t)(2*kp + 1)*D_ + d4);
  }

  for (int t0 = 0; t0 < S_; t0 += BK) {
    __syncthreads();
    // ---- stage prefetched K tile [key][d], fp32->bf16 ----
    #pragma unroll
    for (int i = 0; i < 4; ++i) {
      const int id = tid + 256*i;
      const int key = id >> 4, d4 = (id & 15) * 4;
      const float4 u = kpre[i];
      bf16x4 w; w[0]=f2bf(u.x); w[1]=f2bf(u.y); w[2]=f2bf(u.z); w[3]=f2bf(u.w);
      *(bf16x4*)&sK[key][d4] = w;
    }
    // ---- stage prefetched V^T tile [d][key] ----
    #pragma unroll
    for (int i = 0; i < 2; ++i) {
      const int id = tid + 256*i;
      const int kp = id & 31, d4 = (id >> 5) * 4;
      const float4 a = vpre[2*i];
      const float4 c = vpre[2*i+1];
      const float av[4] = {a.x, a.y, a.z, a.w};
      const float cv[4] = {c.x, c.y, c.z, c.w};
      #pragma unroll
      for (int j = 0; j < 4; ++j) {
        const unsigned pk = (unsigned)(unsigned short)f2bf(av[j])
                          | ((unsigned)(unsigned short)f2bf(cv[j]) << 16);
        *(unsigned*)&sVT[d4 + j][2*kp] = pk;
      }
    }
    __syncthreads();

    // ---- issue next chunk's K/V global loads NOW; latency hides under
    //      compute. Mask for the CURRENT chunk issues here too (L2-resident,
    //      ~200cyc, consumed after the S^T MFMA chain).
    const int tn = t0 + BK;
    int4 mk[4];
    #pragma unroll
    for (int mt = 0; mt < 4; ++mt)
      mk[mt] = *(const int4*)(mrow + t0 + mt*16 + quad*4);
    if (tn < S_) {
      const float* kb = kbase + (size_t)tn * D_;
      const float* vb = vbase + (size_t)tn * D_;
      #pragma unroll
      for (int i = 0; i < 4; ++i) {
        const int id = tid + 256*i;
        kpre[i] = *(const float4*)(kb + (size_t)(id >> 4)*D_ + (id & 15)*4);
      }
      #pragma unroll
      for (int i = 0; i < 2; ++i) {
        const int id = tid + 256*i;
        const int kp = id & 31, d4 = (id >> 5) * 4;
        vpre[2*i]   = *(const float4*)(vb + (size_t)(2*kp    )*D_ + d4);
        vpre[2*i+1] = *(const float4*)(vb + (size_t)(2*kp + 1)*D_ + d4);
      }
    }

    // ---- S^T = K * Q^T : C[row=key=quad*4+r (tile mt)][col=q=l15] ----
    f32x4 st[4];
    #pragma unroll
    for (int mt = 0; mt < 4; ++mt) {
      f32x4 acc = (f32x4){0.f, 0.f, 0.f, 0.f};
      #pragma unroll
      for (int ks = 0; ks < 2; ++ks) {
        const bf16x8 kf = *(const bf16x8*)&sK[mt*16 + l15][ks*32 + quad*8];
        acc = __builtin_amdgcn_mfma_f32_16x16x32_bf16(kf, qf[ks], acc, 0, 0, 0);
      }
      st[mt] = acc;
    }

    // ---- mask + chunk max ----
    float cmax = -3.0e38f;
    #pragma unroll
    for (int mt = 0; mt < 4; ++mt) {
      f32x4 s = st[mt];
      s.x = mk[mt].x ? s.x : MASKNEG;
      s.y = mk[mt].y ? s.y : MASKNEG;
      s.z = mk[mt].z ? s.z : MASKNEG;
      s.w = mk[mt].w ? s.w : MASKNEG;
      st[mt] = s;
      cmax = fmaxf(cmax, fmaxf(fmaxf(s.x, s.y), fmaxf(s.z, s.w)));
    }
    cmax = fmaxf(cmax, __shfl_xor(cmax, 16));   // bijective shuffles: free
    cmax = fmaxf(cmax, __shfl_xor(cmax, 32));
    const float mnew  = fmaxf(m, cmax);
    const float alpha = fexp2(m - mnew);   // ==0 on first chunk (m=-3e38)
    m = mnew;

    // broadcast alpha via per-wave LDS (alpha is quad-uniform per l15)
    if (quad == 0) sA[wv][l15] = alpha;

    // ---- P = exp2(S - m), accumulate l, write P to per-wave LDS ----
    float lsum = 0.f;
    #pragma unroll
    for (int mt = 0; mt < 4; ++mt) {
      const float p0 = fexp2(st[mt].x - mnew);
      const float p1 = fexp2(st[mt].y - mnew);
      const float p2 = fexp2(st[mt].z - mnew);
      const float p3 = fexp2(st[mt].w - mnew);
      lsum += (p0 + p1) + (p2 + p3);
      bf16x4 pw; pw[0]=f2bf(p0); pw[1]=f2bf(p1); pw[2]=f2bf(p2); pw[3]=f2bf(p3);
      *(bf16x4*)&sP[wv][l15][mt*16 + quad*4] = pw;
    }
    // each quad-replica holds only 16/64 chunk keys: reduce across quads
    lsum += __shfl_xor(lsum, 16);
    lsum += __shfl_xor(lsum, 32);
    l = l * alpha + lsum;

    // wave-internal: drain ds ops (sP + sA visible across lanes of this wave)
    asm volatile("s_waitcnt lgkmcnt(0)" ::: "memory");

    // ---- rescale O (O-rows are q=quad*4+r); same-address b128 broadcast ----
    const float4 ar = *(const float4*)&sA[wv][quad*4];
    #pragma unroll
    for (int dt = 0; dt < 4; ++dt) {
      O[dt].x *= ar.x; O[dt].y *= ar.y; O[dt].z *= ar.z; O[dt].w *= ar.w;
    }

    // ---- O += P * V ----
    const bf16x8 pf0 = *(const bf16x8*)&sP[wv][l15][quad*8];
    const bf16x8 pf1 = *(const bf16x8*)&sP[wv][l15][32 + quad*8];
    #pragma unroll
    for (int dt = 0; dt < 4; ++dt) {
      const bf16x8 vf0 = *(const bf16x8*)&sVT[dt*16 + l15][quad*8];
      const bf16x8 vf1 = *(const bf16x8*)&sVT[dt*16 + l15][32 + quad*8];
      O[dt] = __builtin_amdgcn_mfma_f32_16x16x32_bf16(pf0, vf0, O[dt], 0, 0, 0);
      O[dt] = __builtin_amdgcn_mfma_f32_16x16x32_bf16(pf1, vf1, O[dt], 0, 0, 0);
    }
  }

  // ---- epilogue: normalize by l (per O-row), store ----
  if (quad == 0) sA[wv][l15] = l;
  asm volatile("s_waitcnt lgkmcnt(0)" ::: "memory");
  const float4 lv = *(const float4*)&sA[wv][quad*4];
  const float ir0 = 1.0f / lv.x, ir1 = 1.0f / lv.y;
  const float ir2 = 1.0f / lv.z, ir3 = 1.0f / lv.w;

  float* ob = outg + ((size_t)bh * S_ + q0 + wv*16) * D_;
  #pragma unroll
  for (int dt = 0; dt < 4; ++dt) {
    ob[(quad*4 + 0)*D_ + dt*16 + l15] = O[dt].x * ir0;
    ob[(quad*4 + 1)*D_ + dt*16 + l15] = O[dt].y * ir1;
    ob[(quad*4 + 2)*D_ + dt*16 + l15] = O[dt].z * ir2;
    ob[(quad*4 + 3)*D_ + dt*16 + l15] = O[dt].w * ir3;
  }
}

extern "C" void kernel_launch(void* const* d_in, const int* in_sizes, int n_in,
                              void* d_out, int out_size, void* d_ws, size_t ws_size,
                              hipStream_t stream) {
  const float* q    = (const float*)d_in[0];
  const float* k    = (const float*)d_in[1];
  const float* v    = (const float*)d_in[2];
  const int*   mask = (const int*)d_in[3];
  float* out = (float*)d_out;

  dim3 grid(S_ / BQ, B_ * H_);   // (32, 32) = 1024 blocks, 4 waves each
  attn_mfma<<<grid, 256, 0, stream>>>(q, k, v, mask, out);
}

// Round 6
// 241.518 us; speedup vs baseline: 1.4194x; 1.0953x over previous
//
#include <hip/hip_runtime.h>
#include <hip/hip_bf16.h>

// DotProductAttention B=2,H=16,S=2048,D=64 fp32 in/out, int32 mask (B,1,S,S).
// R5: LDS double-buffer, ONE barrier per K-chunk. Compute chunk t from buf A
//     while loading+staging chunk t+1 into buf B (loads issue at compute top,
//     cvt+LDS-write after the PV MFMAs, single __syncthreads at loop end).
//     Register prefetch across compute (R3/R4) lost twice -> the pipeline
//     state lives in LDS, regs only bridge load->stage within one iteration.
//     Back to __launch_bounds__(256,4): R4 proved ~68 VGPR total, fits 128.
//  - S^T = K*Q^T so softmax stats live one-query-per-lane-column.
//  - base-2 softmax (0.125*log2e folded into Q, mask -> -1e9*log2e).
//  - P: C-layout -> A-layout via per-wave LDS round trip.
//  - V transposed in LDS [d][key]; rows 144 B for aligned b128.
//  - SQ_LDS_BANK_CONFLICT 1.15e7 is the b128 8-phase floor (constant across
//    R2/R3/R4) - not a target.

#define B_ 2
#define H_ 16
#define S_ 2048
#define D_ 64
#define BQ 64
#define BK 64
#define NCH (S_ / BK)
#define PADW 72   // LDS row stride in bf16 elems (144 bytes)

typedef __attribute__((ext_vector_type(4))) float f32x4;
typedef __attribute__((ext_vector_type(8))) short bf16x8;
typedef __attribute__((ext_vector_type(4))) short bf16x4;

#define QSCALE 0.1803368801111137f       // 0.125 * log2(e)
#define MASKNEG (-1.4426950408889634e9f) // -1e9 * log2(e)

static __device__ __forceinline__ short f2bf(float f) {
  __hip_bfloat16 h = __float2bfloat16(f);
  short s; __builtin_memcpy(&s, &h, sizeof(s)); return s;
}
static __device__ __forceinline__ float fexp2(float x) {
  return __builtin_amdgcn_exp2f(x);
}

// global -> regs for one 64-key K/V chunk (whole block cooperates)
static __device__ __forceinline__ void load_tiles(int tid, const float* kb,
                                                  const float* vb,
                                                  float4* kpre, float4* vpre) {
  #pragma unroll
  for (int i = 0; i < 4; ++i) {
    const int id = tid + 256*i;
    kpre[i] = *(const float4*)(kb + (size_t)(id >> 4)*D_ + (id & 15)*4);
  }
  #pragma unroll
  for (int i = 0; i < 2; ++i) {
    const int id = tid + 256*i;
    const int kp = id & 31, d4 = (id >> 5) * 4;
    vpre[2*i]   = *(const float4*)(vb + (size_t)(2*kp    )*D_ + d4);
    vpre[2*i+1] = *(const float4*)(vb + (size_t)(2*kp + 1)*D_ + d4);
  }
}

// regs -> LDS: K [key][d] bf16, V^T [d][key] bf16
static __device__ __forceinline__ void stage_tiles(int tid, const float4* kpre,
                                                   const float4* vpre,
                                                   short (*sKb)[PADW],
                                                   short (*sVTb)[PADW]) {
  #pragma unroll
  for (int i = 0; i < 4; ++i) {
    const int id = tid + 256*i;
    const int key = id >> 4, d4 = (id & 15) * 4;
    const float4 u = kpre[i];
    bf16x4 w; w[0]=f2bf(u.x); w[1]=f2bf(u.y); w[2]=f2bf(u.z); w[3]=f2bf(u.w);
    *(bf16x4*)&sKb[key][d4] = w;
  }
  #pragma unroll
  for (int i = 0; i < 2; ++i) {
    const int id = tid + 256*i;
    const int kp = id & 31, d4 = (id >> 5) * 4;
    const float4 a = vpre[2*i];
    const float4 c = vpre[2*i+1];
    const float av[4] = {a.x, a.y, a.z, a.w};
    const float cv[4] = {c.x, c.y, c.z, c.w};
    #pragma unroll
    for (int j = 0; j < 4; ++j) {
      const unsigned pk = (unsigned)(unsigned short)f2bf(av[j])
                        | ((unsigned)(unsigned short)f2bf(cv[j]) << 16);
      *(unsigned*)&sVTb[d4 + j][2*kp] = pk;
    }
  }
}

__global__ __launch_bounds__(256, 4)
void attn_mfma(const float* __restrict__ qg, const float* __restrict__ kg,
               const float* __restrict__ vg, const int* __restrict__ maskg,
               float* __restrict__ outg) {
  __shared__ short sK[2][BK][PADW];   // double-buffered K [key][d]
  __shared__ short sVT[2][D_][PADW];  // double-buffered V^T [d][key]
  __shared__ short sP[4][16][PADW];   // per-wave P [q][key]
  __shared__ float sA[4][16];         // per-wave stats broadcast

  const int tid  = threadIdx.x;
  const int lane = tid & 63;
  const int wv   = tid >> 6;
  const int l15  = lane & 15;
  const int quad = lane >> 4;

  const int bh = blockIdx.y;          // 0..31
  const int b  = bh >> 4;
  const int q0 = blockIdx.x * BQ;
  const int qw = q0 + wv * 16 + l15;  // this lane's stats-query row

  // ---- Q fragments (B-operand: lane holds Q[q=l15][d=ks*32+quad*8+j]) ----
  bf16x8 qf[2];
  {
    const float* qrow = qg + ((size_t)bh * S_ + qw) * D_;
    #pragma unroll
    for (int ks = 0; ks < 2; ++ks) {
      const float4 u0 = *(const float4*)(qrow + ks*32 + quad*8);
      const float4 u1 = *(const float4*)(qrow + ks*32 + quad*8 + 4);
      bf16x8 f;
      f[0]=f2bf(u0.x*QSCALE); f[1]=f2bf(u0.y*QSCALE);
      f[2]=f2bf(u0.z*QSCALE); f[3]=f2bf(u0.w*QSCALE);
      f[4]=f2bf(u1.x*QSCALE); f[5]=f2bf(u1.y*QSCALE);
      f[6]=f2bf(u1.z*QSCALE); f[7]=f2bf(u1.w*QSCALE);
      qf[ks] = f;
    }
  }

  f32x4 O[4];
  #pragma unroll
  for (int dt = 0; dt < 4; ++dt) O[dt] = (f32x4){0.f, 0.f, 0.f, 0.f};
  float m = -3.0e38f, l = 0.f;

  const float* kbase = kg + (size_t)bh * S_ * D_;
  const float* vbase = vg + (size_t)bh * S_ * D_;
  const int*   mrow  = maskg + ((size_t)b * S_ + qw) * S_;

  float4 kpre[4], vpre[4];

  // prologue: chunk 0 -> buf 0
  load_tiles(tid, kbase, vbase, kpre, vpre);
  stage_tiles(tid, kpre, vpre, sK[0], sVT[0]);
  __syncthreads();

  for (int t = 0; t < NCH; ++t) {
    const int cur = t & 1, nxt = cur ^ 1;
    const int t0 = t * BK;
    const bool more = (t + 1 < NCH);

    // issue chunk t+1's global loads first; latency hides under compute
    if (more)
      load_tiles(tid, kbase + (size_t)(t0 + BK) * D_,
                 vbase + (size_t)(t0 + BK) * D_, kpre, vpre);

    // mask for this chunk (L2-resident; consumed after the S^T MFMA chain)
    int4 mk[4];
    #pragma unroll
    for (int mt = 0; mt < 4; ++mt)
      mk[mt] = *(const int4*)(mrow + t0 + mt*16 + quad*4);

    // ---- S^T = K * Q^T : C[row=key=quad*4+r (tile mt)][col=q=l15] ----
    f32x4 st[4];
    #pragma unroll
    for (int mt = 0; mt < 4; ++mt) {
      f32x4 acc = (f32x4){0.f, 0.f, 0.f, 0.f};
      #pragma unroll
      for (int ks = 0; ks < 2; ++ks) {
        const bf16x8 kf = *(const bf16x8*)&sK[cur][mt*16 + l15][ks*32 + quad*8];
        acc = __builtin_amdgcn_mfma_f32_16x16x32_bf16(kf, qf[ks], acc, 0, 0, 0);
      }
      st[mt] = acc;
    }

    // ---- mask + chunk max ----
    float cmax = -3.0e38f;
    #pragma unroll
    for (int mt = 0; mt < 4; ++mt) {
      f32x4 s = st[mt];
      s.x = mk[mt].x ? s.x : MASKNEG;
      s.y = mk[mt].y ? s.y : MASKNEG;
      s.z = mk[mt].z ? s.z : MASKNEG;
      s.w = mk[mt].w ? s.w : MASKNEG;
      st[mt] = s;
      cmax = fmaxf(cmax, fmaxf(fmaxf(s.x, s.y), fmaxf(s.z, s.w)));
    }
    cmax = fmaxf(cmax, __shfl_xor(cmax, 16));   // bijective shuffles
    cmax = fmaxf(cmax, __shfl_xor(cmax, 32));
    const float mnew  = fmaxf(m, cmax);
    const float alpha = fexp2(m - mnew);   // ==0 on first chunk (m=-3e38)
    m = mnew;

    if (quad == 0) sA[wv][l15] = alpha;    // quad-uniform broadcast via LDS

    // ---- P = exp2(S - m), accumulate l, write P to per-wave LDS ----
    float lsum = 0.f;
    #pragma unroll
    for (int mt = 0; mt < 4; ++mt) {
      const float p0 = fexp2(st[mt].x - mnew);
      const float p1 = fexp2(st[mt].y - mnew);
      const float p2 = fexp2(st[mt].z - mnew);
      const float p3 = fexp2(st[mt].w - mnew);
      lsum += (p0 + p1) + (p2 + p3);
      bf16x4 pw; pw[0]=f2bf(p0); pw[1]=f2bf(p1); pw[2]=f2bf(p2); pw[3]=f2bf(p3);
      *(bf16x4*)&sP[wv][l15][mt*16 + quad*4] = pw;
    }
    // each quad-replica holds only 16/64 chunk keys: reduce across quads
    lsum += __shfl_xor(lsum, 16);
    lsum += __shfl_xor(lsum, 32);
    l = l * alpha + lsum;

    // wave-internal: drain ds ops (sP + sA visible across lanes of this wave)
    asm volatile("s_waitcnt lgkmcnt(0)" ::: "memory");

    // ---- rescale O (O-rows are q=quad*4+r); same-address b128 broadcast ----
    const float4 ar = *(const float4*)&sA[wv][quad*4];
    #pragma unroll
    for (int dt = 0; dt < 4; ++dt) {
      O[dt].x *= ar.x; O[dt].y *= ar.y; O[dt].z *= ar.z; O[dt].w *= ar.w;
    }

    // ---- O += P * V ----
    const bf16x8 pf0 = *(const bf16x8*)&sP[wv][l15][quad*8];
    const bf16x8 pf1 = *(const bf16x8*)&sP[wv][l15][32 + quad*8];
    #pragma unroll
    for (int dt = 0; dt < 4; ++dt) {
      const bf16x8 vf0 = *(const bf16x8*)&sVT[cur][dt*16 + l15][quad*8];
      const bf16x8 vf1 = *(const bf16x8*)&sVT[cur][dt*16 + l15][32 + quad*8];
      O[dt] = __builtin_amdgcn_mfma_f32_16x16x32_bf16(pf0, vf0, O[dt], 0, 0, 0);
      O[dt] = __builtin_amdgcn_mfma_f32_16x16x32_bf16(pf1, vf1, O[dt], 0, 0, 0);
    }

    // ---- stage chunk t+1 into the other buffer (disjoint from cur) ----
    if (more) stage_tiles(tid, kpre, vpre, sK[nxt], sVT[nxt]);
    __syncthreads();   // ONE barrier: t's reads done, t+1's buffer complete
  }

  // ---- epilogue: normalize by l (per O-row), store ----
  if (quad == 0) sA[wv][l15] = l;
  asm volatile("s_waitcnt lgkmcnt(0)" ::: "memory");
  const float4 lv = *(const float4*)&sA[wv][quad*4];
  const float ir0 = 1.0f / lv.x, ir1 = 1.0f / lv.y;
  const float ir2 = 1.0f / lv.z, ir3 = 1.0f / lv.w;

  float* ob = outg + ((size_t)bh * S_ + q0 + wv*16) * D_;
  #pragma unroll
  for (int dt = 0; dt < 4; ++dt) {
    ob[(quad*4 + 0)*D_ + dt*16 + l15] = O[dt].x * ir0;
    ob[(quad*4 + 1)*D_ + dt*16 + l15] = O[dt].y * ir1;
    ob[(quad*4 + 2)*D_ + dt*16 + l15] = O[dt].z * ir2;
    ob[(quad*4 + 3)*D_ + dt*16 + l15] = O[dt].w * ir3;
  }
}

extern "C" void kernel_launch(void* const* d_in, const int* in_sizes, int n_in,
                              void* d_out, int out_size, void* d_ws, size_t ws_size,
                              hipStream_t stream) {
  const float* q    = (const float*)d_in[0];
  const float* k    = (const float*)d_in[1];
  const float* v    = (const float*)d_in[2];
  const int*   mask = (const int*)d_in[3];
  float* out = (float*)d_out;

  dim3 grid(S_ / BQ, B_ * H_);   // (32, 32) = 1024 blocks, 4 waves each
  attn_mfma<<<grid, 256, 0, stream>>>(q, k, v, mask, out);
}